// Round 3
// baseline (268.819 us; speedup 1.0000x reference)
//
#include <hip/hip_runtime.h>

#define BS 32
#define NA 8400
#define NMAX 100
#define NC 80
#define TOPK 13
#define EPSF 1e-9f
#define WCAP 1024    // per-wave candidate cap; true max ~400 (mean ~60)

// out layout (float32, concatenated in reference return order)
#define OFF_LBL  0
#define OFF_BOX  (BS*NA)                       // 268800
#define OFF_SCR  (BS*NA + BS*NA*4)             // 1344000
#define OFF_POS  (BS*NA + BS*NA*4 + BS*NA*NC)  // 22848000

#define NROWS (BS*NMAX)                        // 3200 gt rows
#define TKBLK 800                              // topk blocks (4 waves = 4 rows each)
#define ZBLK  250                              // score-zero blocks inside K1
#define NSC4  (BS*NA*NC/4)                     // 5,376,000 float4 in score region

__device__ __forceinline__ float iou_fn(float gx1, float gy1, float gx2, float gy2,
                                        float px1, float py1, float px2, float py2) {
    float lx = fmaxf(gx1, px1), ly = fmaxf(gy1, py1);
    float rx = fminf(gx2, px2), ry = fminf(gy2, py2);
    float w = fmaxf(rx - lx, 0.f), h = fmaxf(ry - ly, 0.f);
    float inter = w * h;
    float aa = (gx2 - gx1) * (gy2 - gy1);
    float ab = (px2 - px1) * (py2 - py1);
    return inter / (aa + ab - inter + EPSF);
}

// K1 (one dispatch, two independent jobs — no interdependence, no memsets):
//  blocks 0..799: ONE WAVE PER (b,j) GT ROW. Phase A scans all 8400 anchors
//    (strip binning removed: saves the whole bin dispatch for ~7us of extra
//    well-parallelized VALU). Phase B: ~60 candidates -> metric + per-lane
//    sorted top-13 register list. Phase C: 13 butterfly extract-max rounds;
//    winners recorded in PER-GT-OWNED claim lists (plain stores into owned
//    slots + count: nothing needs pre-zeroing, unlike the old atomicAdd
//    claims array).
//  blocks 800..1049: zero the 86MB score output region (the dominant
//    mandatory write, overlapped with the latency-bound topk blocks instead
//    of serializing finalize). Block 800 also zeros pa/po (untouched by K1).
__global__ __launch_bounds__(256) void topk_kernel(
    const float* __restrict__ pred_scores,   // BS,NA,NC
    const float* __restrict__ pred_bboxes,   // BS,NA,4
    const float* __restrict__ anchor_points, // NA,2
    const int*   __restrict__ gt_labels,     // BS,NMAX,1
    const float* __restrict__ gt_bboxes,     // BS,NMAX,4
    const float* __restrict__ mask_gt,       // BS,NMAX,1
    unsigned int*   __restrict__ ccount,     // NROWS
    unsigned short* __restrict__ clist,      // NROWS*TOPK
    unsigned int* __restrict__ pa_bits,      // zeroed here, used by K2/K3
    unsigned int* __restrict__ po_bits,
    float* __restrict__ out)
{
    int t = threadIdx.x;
    if (blockIdx.x >= TKBLK) {
        // ---- score-region zero job (86MB, coalesced float4) ----
        int zb = blockIdx.x - TKBLK;
        if (zb == 0) {            // also zero pa/po: 6400 u32 = 1600 uint4
            uint4* pz = (uint4*)pa_bits;   // pa,po contiguous in ws
            uint4 zz = make_uint4(0u, 0u, 0u, 0u);
            for (int i = t; i < 1600; i += 256) pz[i] = zz;
        }
        float4* sz = (float4*)(out + OFF_SCR);
        float4 zf = make_float4(0.f, 0.f, 0.f, 0.f);
        for (int i = zb * 256 + t; i < NSC4; i += ZBLK * 256) sz[i] = zf;
        return;
    }

    __shared__ unsigned short aidx[4][WCAP];
    int wave = t >> 6;
    int lane = t & 63;
    int row = blockIdx.x * 4 + wave;         // 800*4 == 3200 rows exactly
    if (mask_gt[row] <= 0.f) {               // wave-uniform
        if (lane == 0) ccount[row] = 0u;
        return;
    }
    int b = row / NMAX;

    const float* gbp = gt_bboxes + (size_t)row * 4;
    float gx1 = gbp[0], gy1 = gbp[1], gx2 = gbp[2], gy2 = gbp[3];
    int lab = gt_labels[row];

    // Phase A: ballot-compact in-gt anchor indices (wave-private, no atomics)
    const float2* ap2 = (const float2*)anchor_points;
    int cnt = 0;
    for (int base = 0; base < NA; base += 64) {
        int p = base + lane;
        bool hit = false;
        if (p < NA) {
            float2 ap = ap2[p];
            hit = (ap.x - gx1 > EPSF) && (ap.y - gy1 > EPSF) &&
                  (gx2 - ap.x > EPSF) && (gy2 - ap.y > EPSF);
        }
        unsigned long long mb = __ballot(hit);
        if (hit) {
            int my = cnt + __popcll(mb & ((1ULL << lane) - 1ULL));
            if (my < WCAP) aidx[wave][my] = (unsigned short)p;
        }
        cnt += __popcll(mb);   // wave-uniform
    }
    if (cnt > WCAP) cnt = WCAP;

    // Phase B: dense metric pass, per-lane sorted top-13 in registers
    unsigned long long loc[TOPK];
    #pragma unroll
    for (int i = 0; i < TOPK; i++) loc[i] = 0ULL;
    const float4* pb4 = (const float4*)pred_bboxes;
    for (int p = lane; p < cnt; p += 64) {
        int a = aidx[wave][p];
        float4 pb = pb4[b * NA + a];
        float s = pred_scores[((size_t)b * NA + a) * NC + lab];
        float iou = iou_fn(gx1, gy1, gx2, gy2, pb.x, pb.y, pb.z, pb.w);
        float i2 = iou * iou;
        float m = s * (i2 * i2 * i2);
        if (m > 0.f) {
            // (metric<<32)|(NA-a): u64 order == value desc, index asc (jax tie-break)
            unsigned long long key =
                ((unsigned long long)__float_as_uint(m) << 32) |
                (unsigned int)(NA - a);
            #pragma unroll
            for (int i = 0; i < TOPK; i++) {
                if (key > loc[i]) { unsigned long long tmp = loc[i]; loc[i] = key; key = tmp; }
            }
        }
    }

    // Phase C: 13 extract-max rounds; winner writes its OWN row's list slot
    int picks = TOPK;
    for (int r = 0; r < TOPK; r++) {
        unsigned long long h = loc[0];
        unsigned long long m = h;
        #pragma unroll
        for (int s = 32; s > 0; s >>= 1) {
            unsigned long long o = __shfl_xor(m, s, 64);
            m = o > m ? o : m;
        }
        if (m == 0ULL) { picks = r; break; }   // wave-uniform
        unsigned long long ball = __ballot(h == m);  // keys distinct -> one lane
        if (lane == (int)__builtin_ctzll(ball)) {
            #pragma unroll
            for (int i = 0; i < TOPK - 1; i++) loc[i] = loc[i + 1];
            loc[TOPK - 1] = 0ULL;
            int a = NA - (int)(unsigned int)(m & 0xFFFFFFFFULL);
            clist[row * TOPK + r] = (unsigned short)a;
        }
    }
    if (lane == 0) ccount[row] = (unsigned int)picks;
}

// K2: grid (33, BS), 256 threads. Rebuilds the per-anchor packed claim word
// pk = sum over claiming gts of (1<<16)|j — IDENTICAL value to the old global
// atomicAdd array — by inverting the batch's <=1300 claim-list entries into a
// 256-anchor LDS window (6 strided iterations/thread, LDS atomics). Then the
// verified resolution: single-claim reuse, multi-claim argmax-IOU over
// LDS-staged gt boxes; atomicMax align/iou bits per gt.
__global__ __launch_bounds__(256) void resolve_kernel(
    const float* __restrict__ pred_scores,
    const float* __restrict__ pred_bboxes,
    const int*   __restrict__ gt_labels,
    const float* __restrict__ gt_bboxes,
    const unsigned int*   __restrict__ ccount,
    const unsigned short* __restrict__ clist,
    int* __restrict__ assigned_j, float* __restrict__ a_align,
    unsigned int* __restrict__ pa_bits, unsigned int* __restrict__ po_bits)
{
    __shared__ float4 gtb[NMAX];
    __shared__ int    glab[NMAX];
    __shared__ int    ccnt[NMAX];
    __shared__ unsigned int pkl[256];
    int b = blockIdx.y;
    int t = threadIdx.x;
    if (t < NMAX) {
        gtb[t]  = ((const float4*)gt_bboxes)[b * NMAX + t];
        glab[t] = gt_labels[b * NMAX + t];
        ccnt[t] = (int)ccount[b * NMAX + t];
    }
    pkl[t] = 0u;
    __syncthreads();

    int lo = blockIdx.x * 256;
    // invert claim lists into this block's anchor window
    for (int e = t; e < NMAX * TOPK; e += 256) {
        int j = e / TOPK, k = e - j * TOPK;
        if (k < ccnt[j]) {
            int a = clist[(b * NMAX + j) * TOPK + k];
            unsigned int w = (unsigned int)(a - lo);
            if (w < 256u) atomicAdd(&pkl[w], (1u << 16) | (unsigned int)j);
        }
    }
    __syncthreads();

    int ai = lo + t;
    if (ai >= NA) return;
    int idx = b * NA + ai;
    unsigned int pk = pkl[t];
    if (pk == 0u) { assigned_j[idx] = -1; a_align[idx] = 0.f; return; }

    float4 pb = ((const float4*)pred_bboxes)[idx];
    int js; float iou;
    if ((pk >> 16) == 1u) {
        js = (int)(pk & 0xFFFFu);
        float4 g = gtb[js];
        iou = iou_fn(g.x, g.y, g.z, g.w, pb.x, pb.y, pb.z, pb.w);
    } else {
        // reference: overlaps.argmax(axis=1) over ALL gts, first-max wins
        float best = -1.f; js = 0;
        for (int j = 0; j < NMAX; j++) {
            float4 g = gtb[j];
            float v = iou_fn(g.x, g.y, g.z, g.w, pb.x, pb.y, pb.z, pb.w);
            if (v > best) { best = v; js = j; }
        }
        iou = best;
    }
    int lab = glab[js];
    float s = pred_scores[(size_t)idx * NC + lab];
    float i2 = iou * iou;
    float align = s * (i2 * i2 * i2);   // UNMASKED align metric (reference semantics)
    assigned_j[idx] = js; a_align[idx] = align;
    // non-negative floats: uint bit-pattern compare == float compare
    atomicMax(&pa_bits[b * NMAX + js], __float_as_uint(align));
    atomicMax(&po_bits[b * NMAX + js], __float_as_uint(iou));
}

// K3: labels/boxes/pos + one-hot norm scatter. Score region was pre-zeroed in
// K1 (ordering via the two dispatch boundaries), so this writes only ~6.5MB.
__global__ __launch_bounds__(256) void finalize_kernel(
    const int*   __restrict__ gt_labels,
    const float* __restrict__ gt_bboxes,
    const int* __restrict__ assigned_j,
    const float* __restrict__ a_align,
    const unsigned int* __restrict__ pa_bits, const unsigned int* __restrict__ po_bits,
    float* __restrict__ out)
{
    int t = threadIdx.x;
    int idx = blockIdx.x * 256 + t;          // BS*NA divisible by 256
    int b = idx / NA;
    int js = assigned_j[idx];
    bool pos = js >= 0;
    int j0 = pos ? js : 0;   // argmax of all-zero mask_pos -> gt 0
    int lab = gt_labels[b * NMAX + j0];

    out[OFF_LBL + idx] = pos ? (float)lab : (float)NC;
    ((float4*)(out + OFF_BOX))[idx] = ((const float4*)gt_bboxes)[b * NMAX + j0];
    out[OFF_POS + idx] = pos ? 1.f : 0.f;

    if (pos) {
        float pa = __uint_as_float(pa_bits[b * NMAX + js]);
        float po = __uint_as_float(po_bits[b * NMAX + js]);
        out[OFF_SCR + (size_t)idx * NC + lab] = a_align[idx] * po / (pa + EPSF);
    }
}

extern "C" void kernel_launch(void* const* d_in, const int* in_sizes, int n_in,
                              void* d_out, int out_size, void* d_ws, size_t ws_size,
                              hipStream_t stream) {
    const float* pred_scores   = (const float*)d_in[0];
    const float* pred_bboxes   = (const float*)d_in[1];
    const float* anchor_points = (const float*)d_in[2];
    const int*   gt_labels     = (const int*)d_in[3];
    const float* gt_bboxes     = (const float*)d_in[4];
    const float* mask_gt       = (const float*)d_in[5];

    char* ws = (char*)d_ws;
    const size_t NBA = (size_t)BS * NA;           // 268800
    // ws layout (nothing needs host-side init; ws may be poisoned 0xAA):
    //   [pa 3200 u32][po 3200 u32]      <- zeroed by K1 block 800
    //   [ccount 3200 u32]               <- fully written by K1
    //   [clist 3200*13 u16]             <- slots < ccount written by K1
    //   [assigned_j NBA i32][a_align NBA f32]  <- fully written by K2
    unsigned int*   pa_bits = (unsigned int*)(ws);
    unsigned int*   po_bits = (unsigned int*)(ws + 12800);
    unsigned int*   ccount  = (unsigned int*)(ws + 25600);
    unsigned short* clist   = (unsigned short*)(ws + 38400);
    int*   assigned_j = (int*)(ws + 38400 + (size_t)NROWS * TOPK * 2 + 320); // +320: pad to 121920 (16B-aligned)
    float* a_align    = (float*)((char*)assigned_j + NBA * 4);

    float* out = (float*)d_out;

    // 3 dispatches, 0 memsets (was 4 dispatches):
    topk_kernel<<<TKBLK + ZBLK, 256, 0, stream>>>(
        pred_scores, pred_bboxes, anchor_points, gt_labels, gt_bboxes, mask_gt,
        ccount, clist, pa_bits, po_bits, out);

    dim3 rgrid((NA + 255) / 256, BS);
    resolve_kernel<<<rgrid, 256, 0, stream>>>(
        pred_scores, pred_bboxes, gt_labels, gt_bboxes, ccount, clist,
        assigned_j, a_align, pa_bits, po_bits);

    finalize_kernel<<<(int)(NBA / 256), 256, 0, stream>>>(
        gt_labels, gt_bboxes, assigned_j, a_align, pa_bits, po_bits, out);
}

// Round 4
// 245.615 us; speedup vs baseline: 1.0945x; 1.0945x over previous
//
#include <hip/hip_runtime.h>

#define BS 32
#define NA 8400
#define NMAX 100
#define NC 80
#define TOPK 13
#define EPSF 1e-9f
#define WCAP 1024    // per-wave candidate cap; true max ~400 (mean ~60)
#define NSTRIP 64
#define STRIP_INV 0.1f   // 10px y-strips over [0,640)

// out layout (float32, concatenated in reference return order)
#define OFF_LBL  0
#define OFF_BOX  (BS*NA)                       // 268800
#define OFF_SCR  (BS*NA + BS*NA*4)             // 1344000
#define OFF_POS  (BS*NA + BS*NA*4 + BS*NA*NC)  // 22848000

#define NROWS (BS*NMAX)                        // 3200 gt rows
#define NSC4  (BS*NA*NC/4)                     // 5,376,000 float4 in score region
#define ZBLK  120                              // zero blocks in K1 (x1024 thr)

// K1 (121 x 1024): block 0 bins anchors into 64 y-strips, emitting strip-sorted
// float4 (x, y, idx-bits, 0) so topk's phase A is ONE 16B coalesced load per
// anchor (Round-0-verified). Blocks 1..120 zero the 86MB score output region
// (dominant mandatory write, overlapped with binning); block 1 also zeros
// pa/po/pcount (the only ws state needing init).
__global__ __launch_bounds__(1024) void bin_zero_kernel(
    const float* __restrict__ anchor_points,
    int* __restrict__ strip_off, float4* __restrict__ sAPI,
    unsigned int* __restrict__ pz_base,      // pa,po contiguous: 6400 u32
    unsigned int* __restrict__ pcount,
    float* __restrict__ out)
{
    int t = threadIdx.x;
    if (blockIdx.x != 0) {
        int zb = blockIdx.x - 1;
        if (zb == 0) {
            uint4* pz = (uint4*)pz_base;     // 6400 u32 = 1600 uint4
            uint4 zz = make_uint4(0u, 0u, 0u, 0u);
            for (int i = t; i < 1600; i += 1024) pz[i] = zz;
            if (t == 0) *pcount = 0u;
        }
        float4* sz = (float4*)(out + OFF_SCR);
        float4 zf = make_float4(0.f, 0.f, 0.f, 0.f);
        for (int i = zb * 1024 + t; i < NSC4; i += ZBLK * 1024) sz[i] = zf;
        return;
    }

    __shared__ int cnt[NSTRIP];
    __shared__ int cur[NSTRIP];
    if (t < NSTRIP) cnt[t] = 0;
    __syncthreads();
    const float2* ap2 = (const float2*)anchor_points;
    for (int a = t; a < NA; a += 1024) {
        int s = (int)(ap2[a].y * STRIP_INV);
        s = s < 0 ? 0 : (s > NSTRIP - 1 ? NSTRIP - 1 : s);
        atomicAdd(&cnt[s], 1);
    }
    __syncthreads();
    if (t < 64) {   // wave 0: exclusive prefix over 64 strips
        int v = cnt[t];
        int inc = v;
        #pragma unroll
        for (int d = 1; d < 64; d <<= 1) {
            int o = __shfl_up(inc, d, 64);
            if (t >= d) inc += o;
        }
        int excl = inc - v;
        cur[t] = excl; strip_off[t] = excl;
        if (t == 63) strip_off[64] = inc;   // == NA
    }
    __syncthreads();
    for (int a = t; a < NA; a += 1024) {
        float2 p = ap2[a];
        int s = (int)(p.y * STRIP_INV);
        s = s < 0 ? 0 : (s > NSTRIP - 1 ? NSTRIP - 1 : s);
        int pos = atomicAdd(&cur[s], 1);    // order within strip irrelevant
        sAPI[pos] = make_float4(p.x, p.y, __int_as_float(a), 0.f);
    }
}

// K2 (800 x 256): ONE WAVE PER (b,j) GT ROW. Phase A scans only y-strips
// overlapping (gy1,gy2) — one float4 load per anchor, ballot-compact hits
// into wave-private LDS (Round-0-verified). Phase B: ~60 candidates ->
// metric + per-lane sorted top-13 register list. Phase C: 13 butterfly
// extract-max rounds; winners stored in PER-GT-OWNED claim lists
// (Round-3-verified: plain stores into owned slots, nothing pre-zeroed).
__global__ __launch_bounds__(256) void topk_kernel(
    const float* __restrict__ pred_scores,   // BS,NA,NC
    const float* __restrict__ pred_bboxes,   // BS,NA,4
    const int*   __restrict__ gt_labels,     // BS,NMAX,1
    const float* __restrict__ gt_bboxes,     // BS,NMAX,4
    const float* __restrict__ mask_gt,       // BS,NMAX,1
    const int*   __restrict__ strip_off,
    const float4* __restrict__ sAPI,
    unsigned int*   __restrict__ ccount,     // NROWS
    unsigned short* __restrict__ clist)      // NROWS*TOPK
{
    __shared__ unsigned short aidx[4][WCAP];
    int t = threadIdx.x;
    int wave = t >> 6;
    int lane = t & 63;
    int row = blockIdx.x * 4 + wave;         // 800*4 == 3200 rows exactly
    if (mask_gt[row] <= 0.f) {               // wave-uniform, no barriers used
        if (lane == 0) ccount[row] = 0u;
        return;
    }
    int b = row / NMAX;

    const float* gbp = gt_bboxes + (size_t)row * 4;
    float gx1 = gbp[0], gy1 = gbp[1], gx2 = gbp[2], gy2 = gbp[3];
    int lab = gt_labels[row];

    // strip range covering (gy1,gy2): float mul + trunc are monotone, so any
    // anchor passing the exact test lies within [s_lo, s_hi].
    int s_lo = (int)(gy1 * STRIP_INV); s_lo = s_lo < 0 ? 0 : (s_lo > NSTRIP-1 ? NSTRIP-1 : s_lo);
    int s_hi = (int)(gy2 * STRIP_INV); s_hi = s_hi < 0 ? 0 : (s_hi > NSTRIP-1 ? NSTRIP-1 : s_hi);
    int lo = strip_off[s_lo], hi = strip_off[s_hi + 1];

    // Phase A: ballot-compact in-gt anchor indices (wave-private, no atomics)
    int cnt = 0;
    for (int base = lo; base < hi; base += 64) {
        int p = base + lane;
        bool hit = false; int a = 0;
        if (p < hi) {
            float4 ap = sAPI[p];
            a = __float_as_int(ap.z);
            hit = (ap.x - gx1 > EPSF) && (ap.y - gy1 > EPSF) &&
                  (gx2 - ap.x > EPSF) && (gy2 - ap.y > EPSF);
        }
        unsigned long long mb = __ballot(hit);
        if (hit) {
            int my = cnt + __popcll(mb & ((1ULL << lane) - 1ULL));
            if (my < WCAP) aidx[wave][my] = (unsigned short)a;
        }
        cnt += __popcll(mb);   // wave-uniform
    }
    if (cnt > WCAP) cnt = WCAP;

    // Phase B: dense metric pass, per-lane sorted top-13 in registers
    unsigned long long loc[TOPK];
    #pragma unroll
    for (int i = 0; i < TOPK; i++) loc[i] = 0ULL;
    const float4* pb4 = (const float4*)pred_bboxes;
    for (int p = lane; p < cnt; p += 64) {
        int a = aidx[wave][p];
        float4 pb = pb4[b * NA + a];
        float s = pred_scores[((size_t)b * NA + a) * NC + lab];
        float lx = fmaxf(gx1, pb.x), ly = fmaxf(gy1, pb.y);
        float rx = fminf(gx2, pb.z), ry = fminf(gy2, pb.w);
        float w = fmaxf(rx - lx, 0.f), h = fmaxf(ry - ly, 0.f);
        float inter = w * h;
        float aa = (gx2 - gx1) * (gy2 - gy1);
        float ab = (pb.z - pb.x) * (pb.w - pb.y);
        float iou = inter / (aa + ab - inter + EPSF);
        float i2 = iou * iou;
        float m = s * (i2 * i2 * i2);
        if (m > 0.f) {
            // (metric<<32)|(NA-a): u64 order == value desc, index asc (jax tie-break)
            unsigned long long key =
                ((unsigned long long)__float_as_uint(m) << 32) |
                (unsigned int)(NA - a);
            #pragma unroll
            for (int i = 0; i < TOPK; i++) {
                if (key > loc[i]) { unsigned long long tmp = loc[i]; loc[i] = key; key = tmp; }
            }
        }
    }

    // Phase C: 13 extract-max rounds; winner writes its OWN row's list slot
    int picks = TOPK;
    for (int r = 0; r < TOPK; r++) {
        unsigned long long h = loc[0];
        unsigned long long m = h;
        #pragma unroll
        for (int s = 32; s > 0; s >>= 1) {
            unsigned long long o = __shfl_xor(m, s, 64);
            m = o > m ? o : m;
        }
        if (m == 0ULL) { picks = r; break; }   // wave-uniform
        unsigned long long ball = __ballot(h == m);  // keys distinct -> one lane
        if (lane == (int)__builtin_ctzll(ball)) {
            #pragma unroll
            for (int i = 0; i < TOPK - 1; i++) loc[i] = loc[i + 1];
            loc[TOPK - 1] = 0ULL;
            int a = NA - (int)(unsigned int)(m & 0xFFFFFFFFULL);
            clist[row * TOPK + r] = (unsigned short)a;
        }
    }
    if (lane == 0) ccount[row] = (unsigned int)picks;
}

// K3 (33 x BS x 256): rebuild the per-anchor packed claim word
// pk = sum over claiming gts of (1<<16)|j (IDENTICAL to the old atomicAdd
// array) by inverting the batch's <=1300 claim-list entries into a 256-anchor
// LDS window. Resolve (single-claim reuse / multi-claim argmax-IOU over
// LDS-staged gts), then write labels/boxes/pos DIRECTLY (they don't depend on
// pa/po) and append positives to a compact list for the tiny K4 scatter.
// assigned_j / a_align arrays are gone.
__global__ __launch_bounds__(256) void resolve_kernel(
    const float* __restrict__ pred_scores,
    const float* __restrict__ pred_bboxes,
    const int*   __restrict__ gt_labels,
    const float* __restrict__ gt_bboxes,
    const unsigned int*   __restrict__ ccount,
    const unsigned short* __restrict__ clist,
    unsigned int* __restrict__ pa_bits, unsigned int* __restrict__ po_bits,
    unsigned int* __restrict__ pcount, uint4* __restrict__ plist,
    float* __restrict__ out)
{
    __shared__ float4 gtb[NMAX];
    __shared__ int    glab[NMAX];
    __shared__ int    ccnt[NMAX];
    __shared__ unsigned int pkl[256];
    int b = blockIdx.y;
    int t = threadIdx.x;
    if (t < NMAX) {
        gtb[t]  = ((const float4*)gt_bboxes)[b * NMAX + t];
        glab[t] = gt_labels[b * NMAX + t];
        ccnt[t] = (int)ccount[b * NMAX + t];
    }
    pkl[t] = 0u;
    __syncthreads();

    int lo = blockIdx.x * 256;
    // invert claim lists into this block's anchor window (<=1300 entries)
    for (int e = t; e < NMAX * TOPK; e += 256) {
        int j = e / TOPK, k = e - j * TOPK;
        if (k < ccnt[j]) {
            int a = clist[(b * NMAX + j) * TOPK + k];
            unsigned int w = (unsigned int)(a - lo);
            if (w < 256u) atomicAdd(&pkl[w], (1u << 16) | (unsigned int)j);
        }
    }
    __syncthreads();

    int ai = lo + t;
    bool valid = ai < NA;
    int idx = b * NA + (valid ? ai : 0);
    unsigned int pk = valid ? pkl[t] : 0u;

    int js = -1; float align = 0.f; int lab = 0;
    if (pk != 0u) {
        float4 pb = ((const float4*)pred_bboxes)[idx];
        float iou;
        if ((pk >> 16) == 1u) {
            js = (int)(pk & 0xFFFFu);
            float4 g = gtb[js];
            float lx = fmaxf(g.x, pb.x), ly = fmaxf(g.y, pb.y);
            float rx = fminf(g.z, pb.z), ry = fminf(g.w, pb.w);
            float w = fmaxf(rx - lx, 0.f), h = fmaxf(ry - ly, 0.f);
            float inter = w * h;
            float aa = (g.z - g.x) * (g.w - g.y);
            float ab = (pb.z - pb.x) * (pb.w - pb.y);
            iou = inter / (aa + ab - inter + EPSF);
        } else {
            // reference: overlaps.argmax(axis=1) over ALL gts, first-max wins
            float best = -1.f; js = 0;
            for (int j = 0; j < NMAX; j++) {
                float4 g = gtb[j];
                float lx = fmaxf(g.x, pb.x), ly = fmaxf(g.y, pb.y);
                float rx = fminf(g.z, pb.z), ry = fminf(g.w, pb.w);
                float w = fmaxf(rx - lx, 0.f), h = fmaxf(ry - ly, 0.f);
                float inter = w * h;
                float aa = (g.z - g.x) * (g.w - g.y);
                float ab = (pb.z - pb.x) * (pb.w - pb.y);
                float v = inter / (aa + ab - inter + EPSF);
                if (v > best) { best = v; js = j; }
            }
            iou = best;
        }
        lab = glab[js];
        float s = pred_scores[(size_t)idx * NC + lab];
        float i2 = iou * iou;
        align = s * (i2 * i2 * i2);   // UNMASKED align metric (reference semantics)
        // non-negative floats: uint bit-pattern compare == float compare
        atomicMax(&pa_bits[b * NMAX + js], __float_as_uint(align));
        atomicMax(&po_bits[b * NMAX + js], __float_as_uint(iou));
    }

    if (valid) {
        bool pos = js >= 0;
        int j0 = pos ? js : 0;   // argmax of all-zero mask_pos -> gt 0
        int albl = pos ? lab : glab[0];
        out[OFF_LBL + idx] = pos ? (float)albl : (float)NC;
        ((float4*)(out + OFF_BOX))[idx] = gtb[j0];
        out[OFF_POS + idx] = pos ? 1.f : 0.f;
    }

    // wave-aggregated positives append: one atomicAdd per wave
    bool pos = valid && js >= 0;
    unsigned long long mb = __ballot(pos);
    int n = __popcll(mb);
    if (n > 0) {
        int lane = t & 63;
        int leader = (int)__builtin_ctzll(mb);
        unsigned int base = 0;
        if (lane == leader) base = atomicAdd(pcount, (unsigned int)n);
        base = (unsigned int)__shfl((int)base, leader, 64);
        if (pos) {
            unsigned int myoff = (unsigned int)__popcll(mb & ((1ULL << (t & 63)) - 1ULL));
            plist[base + myoff] = make_uint4((unsigned int)idx,
                                             (unsigned int)(b * NMAX + js),
                                             __float_as_uint(align),
                                             (unsigned int)lab);
        }
    }
}

// K4 (64 x 256): tiny scatter over ~30K positives. Score region pre-zeroed in
// K1; per-gt pa/po complete after K3's dispatch boundary.
__global__ __launch_bounds__(256) void scatter_kernel(
    const unsigned int* __restrict__ pcount, const uint4* __restrict__ plist,
    const unsigned int* __restrict__ pa_bits, const unsigned int* __restrict__ po_bits,
    float* __restrict__ out)
{
    int n = (int)*pcount;
    for (int i = blockIdx.x * 256 + threadIdx.x; i < n; i += 64 * 256) {
        uint4 e = plist[i];
        float pa = __uint_as_float(pa_bits[e.y]);
        float po = __uint_as_float(po_bits[e.y]);
        float norm = __uint_as_float(e.z) * po / (pa + EPSF);
        out[OFF_SCR + (size_t)e.x * NC + e.w] = norm;
    }
}

extern "C" void kernel_launch(void* const* d_in, const int* in_sizes, int n_in,
                              void* d_out, int out_size, void* d_ws, size_t ws_size,
                              hipStream_t stream) {
    const float* pred_scores   = (const float*)d_in[0];
    const float* pred_bboxes   = (const float*)d_in[1];
    const float* anchor_points = (const float*)d_in[2];
    const int*   gt_labels     = (const int*)d_in[3];
    const float* gt_bboxes     = (const float*)d_in[4];
    const float* mask_gt       = (const float*)d_in[5];

    char* ws = (char*)d_ws;
    // ws layout (no host-side init; ws may be poisoned 0xAA each launch):
    //   [pa 3200 u32][po 3200 u32]        <- zeroed by K1 block 1
    //   [ccount 3200 u32]                 <- fully written by K2
    //   [clist 3200*13 u16]               <- slots < ccount written by K2
    //   [strip_off 65 int (512B pad)][sAPI 8400 float4]  <- written by K1 blk 0
    //   [pcount u32 (16B pad)]            <- zeroed by K1 block 1
    //   [plist 41600 uint4]               <- slots < pcount written by K3
    unsigned int*   pa_bits = (unsigned int*)(ws);
    unsigned int*   po_bits = (unsigned int*)(ws + 12800);
    unsigned int*   ccount  = (unsigned int*)(ws + 25600);
    unsigned short* clist   = (unsigned short*)(ws + 38400);
    int*    strip_off = (int*)(ws + 121600);             // 38400+83200
    float4* sAPI      = (float4*)(ws + 122112);          // +512 pad
    unsigned int* pcount = (unsigned int*)(ws + 256512); // +8400*16
    uint4*  plist     = (uint4*)(ws + 256528);

    float* out = (float*)d_out;

    // 4 dispatches, 0 memsets:
    bin_zero_kernel<<<1 + ZBLK, 1024, 0, stream>>>(
        anchor_points, strip_off, sAPI, pa_bits, pcount, out);

    topk_kernel<<<NROWS / 4, 256, 0, stream>>>(
        pred_scores, pred_bboxes, gt_labels, gt_bboxes, mask_gt,
        strip_off, sAPI, ccount, clist);

    dim3 rgrid((NA + 255) / 256, BS);
    resolve_kernel<<<rgrid, 256, 0, stream>>>(
        pred_scores, pred_bboxes, gt_labels, gt_bboxes, ccount, clist,
        pa_bits, po_bits, pcount, plist, out);

    scatter_kernel<<<64, 256, 0, stream>>>(pcount, plist, pa_bits, po_bits, out);
}

// Round 5
// 244.792 us; speedup vs baseline: 1.0982x; 1.0034x over previous
//
#include <hip/hip_runtime.h>

#define BS 32
#define NA 8400
#define NMAX 100
#define NC 80
#define TOPK 13
#define EPSF 1e-9f
#define WCAP 1024    // per-wave candidate cap; true max ~400 (mean ~60)
#define NSTRIP 64
#define STRIP_INV 0.1f   // 10px y-strips over [0,640)

// out layout (float32, concatenated in reference return order)
#define OFF_LBL  0
#define OFF_BOX  (BS*NA)                       // 268800
#define OFF_SCR  (BS*NA + BS*NA*4)             // 1344000
#define OFF_POS  (BS*NA + BS*NA*4 + BS*NA*NC)  // 22848000

#define NROWS (BS*NMAX)                        // 3200 gt rows
#define NSC4  (BS*NA*NC/4)                     // 5,376,000 float4 in score region
#define ZBLK  511                              // zero blocks in K1 (x1024 thr)
                                               // (was 120: only 47% of CUs -> ~3TB/s;
                                               //  511 -> all CUs, ~6TB/s, ~15us)

// K1 (512 x 1024): block 0 bins anchors into 64 y-strips, emitting strip-sorted
// float4 (x, y, idx-bits, 0) so topk's phase A is ONE 16B coalesced load per
// anchor. Blocks 1..511 zero the 86MB score output region (dominant mandatory
// write, overlapped with binning); block 1 also zeros pa/po/pcount.
__global__ __launch_bounds__(1024) void bin_zero_kernel(
    const float* __restrict__ anchor_points,
    int* __restrict__ strip_off, float4* __restrict__ sAPI,
    unsigned int* __restrict__ pz_base,      // pa,po contiguous: 6400 u32
    unsigned int* __restrict__ pcount,
    float* __restrict__ out)
{
    int t = threadIdx.x;
    if (blockIdx.x != 0) {
        int zb = blockIdx.x - 1;
        if (zb == 0) {
            uint4* pz = (uint4*)pz_base;     // 6400 u32 = 1600 uint4
            uint4 zz = make_uint4(0u, 0u, 0u, 0u);
            for (int i = t; i < 1600; i += 1024) pz[i] = zz;
            if (t == 0) *pcount = 0u;
        }
        float4* sz = (float4*)(out + OFF_SCR);
        float4 zf = make_float4(0.f, 0.f, 0.f, 0.f);
        for (int i = zb * 1024 + t; i < NSC4; i += ZBLK * 1024) sz[i] = zf;
        return;
    }

    __shared__ int cnt[NSTRIP];
    __shared__ int cur[NSTRIP];
    if (t < NSTRIP) cnt[t] = 0;
    __syncthreads();
    const float2* ap2 = (const float2*)anchor_points;
    for (int a = t; a < NA; a += 1024) {
        int s = (int)(ap2[a].y * STRIP_INV);
        s = s < 0 ? 0 : (s > NSTRIP - 1 ? NSTRIP - 1 : s);
        atomicAdd(&cnt[s], 1);
    }
    __syncthreads();
    if (t < 64) {   // wave 0: exclusive prefix over 64 strips
        int v = cnt[t];
        int inc = v;
        #pragma unroll
        for (int d = 1; d < 64; d <<= 1) {
            int o = __shfl_up(inc, d, 64);
            if (t >= d) inc += o;
        }
        int excl = inc - v;
        cur[t] = excl; strip_off[t] = excl;
        if (t == 63) strip_off[64] = inc;   // == NA
    }
    __syncthreads();
    for (int a = t; a < NA; a += 1024) {
        float2 p = ap2[a];
        int s = (int)(p.y * STRIP_INV);
        s = s < 0 ? 0 : (s > NSTRIP - 1 ? NSTRIP - 1 : s);
        int pos = atomicAdd(&cur[s], 1);    // order within strip irrelevant
        sAPI[pos] = make_float4(p.x, p.y, __int_as_float(a), 0.f);
    }
}

// K2 (800 x 256): ONE WAVE PER (b,j) GT ROW — verified 3 rounds, unchanged.
__global__ __launch_bounds__(256) void topk_kernel(
    const float* __restrict__ pred_scores,   // BS,NA,NC
    const float* __restrict__ pred_bboxes,   // BS,NA,4
    const int*   __restrict__ gt_labels,     // BS,NMAX,1
    const float* __restrict__ gt_bboxes,     // BS,NMAX,4
    const float* __restrict__ mask_gt,       // BS,NMAX,1
    const int*   __restrict__ strip_off,
    const float4* __restrict__ sAPI,
    unsigned int*   __restrict__ ccount,     // NROWS
    unsigned short* __restrict__ clist)      // NROWS*TOPK
{
    __shared__ unsigned short aidx[4][WCAP];
    int t = threadIdx.x;
    int wave = t >> 6;
    int lane = t & 63;
    int row = blockIdx.x * 4 + wave;         // 800*4 == 3200 rows exactly
    if (mask_gt[row] <= 0.f) {               // wave-uniform, no barriers used
        if (lane == 0) ccount[row] = 0u;
        return;
    }
    int b = row / NMAX;

    const float* gbp = gt_bboxes + (size_t)row * 4;
    float gx1 = gbp[0], gy1 = gbp[1], gx2 = gbp[2], gy2 = gbp[3];
    int lab = gt_labels[row];

    // strip range covering (gy1,gy2): float mul + trunc are monotone, so any
    // anchor passing the exact test lies within [s_lo, s_hi].
    int s_lo = (int)(gy1 * STRIP_INV); s_lo = s_lo < 0 ? 0 : (s_lo > NSTRIP-1 ? NSTRIP-1 : s_lo);
    int s_hi = (int)(gy2 * STRIP_INV); s_hi = s_hi < 0 ? 0 : (s_hi > NSTRIP-1 ? NSTRIP-1 : s_hi);
    int lo = strip_off[s_lo], hi = strip_off[s_hi + 1];

    // Phase A: ballot-compact in-gt anchor indices (wave-private, no atomics)
    int cnt = 0;
    for (int base = lo; base < hi; base += 64) {
        int p = base + lane;
        bool hit = false; int a = 0;
        if (p < hi) {
            float4 ap = sAPI[p];
            a = __float_as_int(ap.z);
            hit = (ap.x - gx1 > EPSF) && (ap.y - gy1 > EPSF) &&
                  (gx2 - ap.x > EPSF) && (gy2 - ap.y > EPSF);
        }
        unsigned long long mb = __ballot(hit);
        if (hit) {
            int my = cnt + __popcll(mb & ((1ULL << lane) - 1ULL));
            if (my < WCAP) aidx[wave][my] = (unsigned short)a;
        }
        cnt += __popcll(mb);   // wave-uniform
    }
    if (cnt > WCAP) cnt = WCAP;

    // Phase B: dense metric pass, per-lane sorted top-13 in registers
    unsigned long long loc[TOPK];
    #pragma unroll
    for (int i = 0; i < TOPK; i++) loc[i] = 0ULL;
    const float4* pb4 = (const float4*)pred_bboxes;
    for (int p = lane; p < cnt; p += 64) {
        int a = aidx[wave][p];
        float4 pb = pb4[b * NA + a];
        float s = pred_scores[((size_t)b * NA + a) * NC + lab];
        float lx = fmaxf(gx1, pb.x), ly = fmaxf(gy1, pb.y);
        float rx = fminf(gx2, pb.z), ry = fminf(gy2, pb.w);
        float w = fmaxf(rx - lx, 0.f), h = fmaxf(ry - ly, 0.f);
        float inter = w * h;
        float aa = (gx2 - gx1) * (gy2 - gy1);
        float ab = (pb.z - pb.x) * (pb.w - pb.y);
        float iou = inter / (aa + ab - inter + EPSF);
        float i2 = iou * iou;
        float m = s * (i2 * i2 * i2);
        if (m > 0.f) {
            // (metric<<32)|(NA-a): u64 order == value desc, index asc (jax tie-break)
            unsigned long long key =
                ((unsigned long long)__float_as_uint(m) << 32) |
                (unsigned int)(NA - a);
            #pragma unroll
            for (int i = 0; i < TOPK; i++) {
                if (key > loc[i]) { unsigned long long tmp = loc[i]; loc[i] = key; key = tmp; }
            }
        }
    }

    // Phase C: 13 extract-max rounds; winner writes its OWN row's list slot
    int picks = TOPK;
    for (int r = 0; r < TOPK; r++) {
        unsigned long long h = loc[0];
        unsigned long long m = h;
        #pragma unroll
        for (int s = 32; s > 0; s >>= 1) {
            unsigned long long o = __shfl_xor(m, s, 64);
            m = o > m ? o : m;
        }
        if (m == 0ULL) { picks = r; break; }   // wave-uniform
        unsigned long long ball = __ballot(h == m);  // keys distinct -> one lane
        if (lane == (int)__builtin_ctzll(ball)) {
            #pragma unroll
            for (int i = 0; i < TOPK - 1; i++) loc[i] = loc[i + 1];
            loc[TOPK - 1] = 0ULL;
            int a = NA - (int)(unsigned int)(m & 0xFFFFFFFFULL);
            clist[row * TOPK + r] = (unsigned short)a;
        }
    }
    if (lane == 0) ccount[row] = (unsigned int)picks;
}

// K3 (33 x BS x 256): claim inversion + resolution. Round-5 changes vs the
// 56us profile: (a) pred_bboxes PREFETCHED before the staging syncs (hides
// ~900cy HBM latency under inversion); (b) multi-claim argmax is COOPERATIVE:
// the wave processes each multi-claim lane with all 64 lanes sharing the
// 100 IOUs (2/lane + butterfly key-max) instead of a divergent serial
// 100-iteration fmax chain per lane (~40 insts vs ~1500). Tie-break: key =
// (iou_bits<<32)|(99-j) -> max picks smallest j on exact ties == jax argmax
// first-max == the old serial (v > best) loop. IOUs are >=0 so bit compare
// == float compare.
__global__ __launch_bounds__(256) void resolve_kernel(
    const float* __restrict__ pred_scores,
    const float* __restrict__ pred_bboxes,
    const int*   __restrict__ gt_labels,
    const float* __restrict__ gt_bboxes,
    const unsigned int*   __restrict__ ccount,
    const unsigned short* __restrict__ clist,
    unsigned int* __restrict__ pa_bits, unsigned int* __restrict__ po_bits,
    unsigned int* __restrict__ pcount, uint4* __restrict__ plist,
    float* __restrict__ out)
{
    __shared__ float4 gtb[NMAX];
    __shared__ int    glab[NMAX];
    __shared__ int    ccnt[NMAX];
    __shared__ unsigned int pkl[256];
    int b = blockIdx.y;
    int t = threadIdx.x;
    int lane = t & 63;
    int lo = blockIdx.x * 256;
    int ai = lo + t;
    bool valid = ai < NA;
    int idx = b * NA + (valid ? ai : 0);

    // issue the coalesced per-anchor box load FIRST (covered by staging+sync)
    float4 pb = ((const float4*)pred_bboxes)[idx];

    if (t < NMAX) {
        gtb[t]  = ((const float4*)gt_bboxes)[b * NMAX + t];
        glab[t] = gt_labels[b * NMAX + t];
        ccnt[t] = (int)ccount[b * NMAX + t];
    }
    pkl[t] = 0u;
    __syncthreads();

    // invert claim lists into this block's anchor window (<=1300 entries)
    for (int e = t; e < NMAX * TOPK; e += 256) {
        int j = e / TOPK, k = e - j * TOPK;
        if (k < ccnt[j]) {
            int a = clist[(b * NMAX + j) * TOPK + k];
            unsigned int w = (unsigned int)(a - lo);
            if (w < 256u) atomicAdd(&pkl[w], (1u << 16) | (unsigned int)j);
        }
    }
    __syncthreads();

    unsigned int pk = valid ? pkl[t] : 0u;
    int js = -1; float iou = 0.f;

    if ((pk >> 16) == 1u) {          // single claim: direct reuse
        js = (int)(pk & 0xFFFFu);
        float4 g = gtb[js];
        float lx = fmaxf(g.x, pb.x), ly = fmaxf(g.y, pb.y);
        float rx = fminf(g.z, pb.z), ry = fminf(g.w, pb.w);
        float w = fmaxf(rx - lx, 0.f), h = fmaxf(ry - ly, 0.f);
        float inter = w * h;
        float aa = (g.z - g.x) * (g.w - g.y);
        float ab = (pb.z - pb.x) * (pb.w - pb.y);
        iou = inter / (aa + ab - inter + EPSF);
    }

    // cooperative multi-claim resolution (wave-uniform loop, ~1 hit/wave avg)
    unsigned long long mm = __ballot((pk >> 16) > 1u);
    while (mm) {
        int src = (int)__builtin_ctzll(mm);
        mm &= mm - 1ULL;
        float qx1 = __shfl(pb.x, src, 64), qy1 = __shfl(pb.y, src, 64);
        float qx2 = __shfl(pb.z, src, 64), qy2 = __shfl(pb.w, src, 64);
        float qab = (qx2 - qx1) * (qy2 - qy1);
        unsigned long long bestkey = 0ULL;
        #pragma unroll
        for (int rep = 0; rep < 2; rep++) {       // j = lane, lane+64 (<100)
            int j = lane + rep * 64;
            if (j < NMAX) {
                float4 g = gtb[j];
                float lx = fmaxf(g.x, qx1), ly = fmaxf(g.y, qy1);
                float rx = fminf(g.z, qx2), ry = fminf(g.w, qy2);
                float w = fmaxf(rx - lx, 0.f), h = fmaxf(ry - ly, 0.f);
                float inter = w * h;
                float aa = (g.z - g.x) * (g.w - g.y);
                float v = inter / (aa + qab - inter + EPSF);
                unsigned long long key =
                    ((unsigned long long)__float_as_uint(v) << 32) |
                    (unsigned int)(NMAX - 1 - j);
                if (key > bestkey) bestkey = key;
            }
        }
        #pragma unroll
        for (int s = 32; s > 0; s >>= 1) {
            unsigned long long o = __shfl_xor(bestkey, s, 64);
            bestkey = o > bestkey ? o : bestkey;
        }
        if (lane == src) {
            js  = NMAX - 1 - (int)(unsigned int)(bestkey & 0xFFFFFFFFULL);
            iou = __uint_as_float((unsigned int)(bestkey >> 32));
        }
    }

    float align = 0.f; int lab = 0;
    if (js >= 0) {
        lab = glab[js];
        float s = pred_scores[(size_t)idx * NC + lab];
        float i2 = iou * iou;
        align = s * (i2 * i2 * i2);   // UNMASKED align metric (reference semantics)
        // non-negative floats: uint bit-pattern compare == float compare
        atomicMax(&pa_bits[b * NMAX + js], __float_as_uint(align));
        atomicMax(&po_bits[b * NMAX + js], __float_as_uint(iou));
    }

    if (valid) {
        bool pos = js >= 0;
        int j0 = pos ? js : 0;   // argmax of all-zero mask_pos -> gt 0
        out[OFF_LBL + idx] = pos ? (float)glab[j0] : (float)NC;
        ((float4*)(out + OFF_BOX))[idx] = gtb[j0];
        out[OFF_POS + idx] = pos ? 1.f : 0.f;
    }

    // wave-aggregated positives append: one atomicAdd per wave
    bool pos = valid && js >= 0;
    unsigned long long mb = __ballot(pos);
    int n = __popcll(mb);
    if (n > 0) {
        int leader = (int)__builtin_ctzll(mb);
        unsigned int base = 0;
        if (lane == leader) base = atomicAdd(pcount, (unsigned int)n);
        base = (unsigned int)__shfl((int)base, leader, 64);
        if (pos) {
            unsigned int myoff = (unsigned int)__popcll(mb & ((1ULL << lane) - 1ULL));
            plist[base + myoff] = make_uint4((unsigned int)idx,
                                             (unsigned int)(b * NMAX + js),
                                             __float_as_uint(align),
                                             (unsigned int)lab);
        }
    }
}

// K4 (64 x 256): tiny scatter over ~30K positives. Score region pre-zeroed in
// K1; per-gt pa/po complete after K3's dispatch boundary.
__global__ __launch_bounds__(256) void scatter_kernel(
    const unsigned int* __restrict__ pcount, const uint4* __restrict__ plist,
    const unsigned int* __restrict__ pa_bits, const unsigned int* __restrict__ po_bits,
    float* __restrict__ out)
{
    int n = (int)*pcount;
    for (int i = blockIdx.x * 256 + threadIdx.x; i < n; i += 64 * 256) {
        uint4 e = plist[i];
        float pa = __uint_as_float(pa_bits[e.y]);
        float po = __uint_as_float(po_bits[e.y]);
        float norm = __uint_as_float(e.z) * po / (pa + EPSF);
        out[OFF_SCR + (size_t)e.x * NC + e.w] = norm;
    }
}

extern "C" void kernel_launch(void* const* d_in, const int* in_sizes, int n_in,
                              void* d_out, int out_size, void* d_ws, size_t ws_size,
                              hipStream_t stream) {
    const float* pred_scores   = (const float*)d_in[0];
    const float* pred_bboxes   = (const float*)d_in[1];
    const float* anchor_points = (const float*)d_in[2];
    const int*   gt_labels     = (const int*)d_in[3];
    const float* gt_bboxes     = (const float*)d_in[4];
    const float* mask_gt       = (const float*)d_in[5];

    char* ws = (char*)d_ws;
    // ws layout (no host-side init; ws may be poisoned 0xAA each launch):
    //   [pa 3200 u32][po 3200 u32]        <- zeroed by K1 block 1
    //   [ccount 3200 u32]                 <- fully written by K2
    //   [clist 3200*13 u16]               <- slots < ccount written by K2
    //   [strip_off 65 int (512B pad)][sAPI 8400 float4]  <- written by K1 blk 0
    //   [pcount u32 (16B pad)]            <- zeroed by K1 block 1
    //   [plist 41600 uint4]               <- slots < pcount written by K3
    unsigned int*   pa_bits = (unsigned int*)(ws);
    unsigned int*   po_bits = (unsigned int*)(ws + 12800);
    unsigned int*   ccount  = (unsigned int*)(ws + 25600);
    unsigned short* clist   = (unsigned short*)(ws + 38400);
    int*    strip_off = (int*)(ws + 121600);             // 38400+83200
    float4* sAPI      = (float4*)(ws + 122112);          // +512 pad
    unsigned int* pcount = (unsigned int*)(ws + 256512); // +8400*16
    uint4*  plist     = (uint4*)(ws + 256528);

    float* out = (float*)d_out;

    // 4 dispatches, 0 memsets:
    bin_zero_kernel<<<1 + ZBLK, 1024, 0, stream>>>(
        anchor_points, strip_off, sAPI, pa_bits, pcount, out);

    topk_kernel<<<NROWS / 4, 256, 0, stream>>>(
        pred_scores, pred_bboxes, gt_labels, gt_bboxes, mask_gt,
        strip_off, sAPI, ccount, clist);

    dim3 rgrid((NA + 255) / 256, BS);
    resolve_kernel<<<rgrid, 256, 0, stream>>>(
        pred_scores, pred_bboxes, gt_labels, gt_bboxes, ccount, clist,
        pa_bits, po_bits, pcount, plist, out);

    scatter_kernel<<<64, 256, 0, stream>>>(pcount, plist, pa_bits, po_bits, out);
}

// Round 6
// 200.819 us; speedup vs baseline: 1.3386x; 1.2190x over previous
//
#include <hip/hip_runtime.h>

#define BS 32
#define NA 8400
#define NMAX 100
#define NC 80
#define TOPK 13
#define EPSF 1e-9f
#define WCAP 1024    // per-wave candidate cap; true max ~400 (mean ~60)
#define NSTRIP 64
#define STRIP_INV 0.1f   // 10px y-strips over [0,640)

// out layout (float32, concatenated in reference return order)
#define OFF_LBL  0
#define OFF_BOX  (BS*NA)                       // 268800
#define OFF_SCR  (BS*NA + BS*NA*4)             // 1344000
#define OFF_POS  (BS*NA + BS*NA*4 + BS*NA*NC)  // 22848000

#define NROWS (BS*NMAX)                        // 3200 gt rows
#define NSC4  (BS*NA*NC/4)                     // 5,376,000 float4 in score region
#define ZBLK  511                              // zero blocks in K1 (x1024 thr)
#define NCHUNK 33                              // ceil(NA/256) resolve chunks
#define NWID  (BS*NCHUNK*4)                    // 4224 resolve waves

// K1 (512 x 1024): block 0 bins anchors into 64 y-strips, emitting strip-sorted
// float4 (x, y, idx-bits, 0) so topk's phase A is ONE 16B coalesced load per
// anchor. Blocks 1..511 zero the 86MB score output region (dominant mandatory
// write, overlapped with binning); block 1 also zeros pa/po.
__global__ __launch_bounds__(1024) void bin_zero_kernel(
    const float* __restrict__ anchor_points,
    int* __restrict__ strip_off, float4* __restrict__ sAPI,
    unsigned int* __restrict__ pz_base,      // pa,po contiguous: 6400 u32
    float* __restrict__ out)
{
    int t = threadIdx.x;
    if (blockIdx.x != 0) {
        int zb = blockIdx.x - 1;
        if (zb == 0) {
            uint4* pz = (uint4*)pz_base;     // 6400 u32 = 1600 uint4
            uint4 zz = make_uint4(0u, 0u, 0u, 0u);
            for (int i = t; i < 1600; i += 1024) pz[i] = zz;
        }
        float4* sz = (float4*)(out + OFF_SCR);
        float4 zf = make_float4(0.f, 0.f, 0.f, 0.f);
        for (int i = zb * 1024 + t; i < NSC4; i += ZBLK * 1024) sz[i] = zf;
        return;
    }

    __shared__ int cnt[NSTRIP];
    __shared__ int cur[NSTRIP];
    if (t < NSTRIP) cnt[t] = 0;
    __syncthreads();
    const float2* ap2 = (const float2*)anchor_points;
    for (int a = t; a < NA; a += 1024) {
        int s = (int)(ap2[a].y * STRIP_INV);
        s = s < 0 ? 0 : (s > NSTRIP - 1 ? NSTRIP - 1 : s);
        atomicAdd(&cnt[s], 1);
    }
    __syncthreads();
    if (t < 64) {   // wave 0: exclusive prefix over 64 strips
        int v = cnt[t];
        int inc = v;
        #pragma unroll
        for (int d = 1; d < 64; d <<= 1) {
            int o = __shfl_up(inc, d, 64);
            if (t >= d) inc += o;
        }
        int excl = inc - v;
        cur[t] = excl; strip_off[t] = excl;
        if (t == 63) strip_off[64] = inc;   // == NA
    }
    __syncthreads();
    for (int a = t; a < NA; a += 1024) {
        float2 p = ap2[a];
        int s = (int)(p.y * STRIP_INV);
        s = s < 0 ? 0 : (s > NSTRIP - 1 ? NSTRIP - 1 : s);
        int pos = atomicAdd(&cur[s], 1);    // order within strip irrelevant
        sAPI[pos] = make_float4(p.x, p.y, __int_as_float(a), 0.f);
    }
}

// K2 (800 x 256): ONE WAVE PER (b,j) GT ROW — verified 4 rounds, unchanged.
__global__ __launch_bounds__(256) void topk_kernel(
    const float* __restrict__ pred_scores,   // BS,NA,NC
    const float* __restrict__ pred_bboxes,   // BS,NA,4
    const int*   __restrict__ gt_labels,     // BS,NMAX,1
    const float* __restrict__ gt_bboxes,     // BS,NMAX,4
    const float* __restrict__ mask_gt,       // BS,NMAX,1
    const int*   __restrict__ strip_off,
    const float4* __restrict__ sAPI,
    unsigned int*   __restrict__ ccount,     // NROWS
    unsigned short* __restrict__ clist)      // NROWS*TOPK
{
    __shared__ unsigned short aidx[4][WCAP];
    int t = threadIdx.x;
    int wave = t >> 6;
    int lane = t & 63;
    int row = blockIdx.x * 4 + wave;         // 800*4 == 3200 rows exactly
    if (mask_gt[row] <= 0.f) {               // wave-uniform, no barriers used
        if (lane == 0) ccount[row] = 0u;
        return;
    }
    int b = row / NMAX;

    const float* gbp = gt_bboxes + (size_t)row * 4;
    float gx1 = gbp[0], gy1 = gbp[1], gx2 = gbp[2], gy2 = gbp[3];
    int lab = gt_labels[row];

    // strip range covering (gy1,gy2): float mul + trunc are monotone, so any
    // anchor passing the exact test lies within [s_lo, s_hi].
    int s_lo = (int)(gy1 * STRIP_INV); s_lo = s_lo < 0 ? 0 : (s_lo > NSTRIP-1 ? NSTRIP-1 : s_lo);
    int s_hi = (int)(gy2 * STRIP_INV); s_hi = s_hi < 0 ? 0 : (s_hi > NSTRIP-1 ? NSTRIP-1 : s_hi);
    int lo = strip_off[s_lo], hi = strip_off[s_hi + 1];

    // Phase A: ballot-compact in-gt anchor indices (wave-private, no atomics)
    int cnt = 0;
    for (int base = lo; base < hi; base += 64) {
        int p = base + lane;
        bool hit = false; int a = 0;
        if (p < hi) {
            float4 ap = sAPI[p];
            a = __float_as_int(ap.z);
            hit = (ap.x - gx1 > EPSF) && (ap.y - gy1 > EPSF) &&
                  (gx2 - ap.x > EPSF) && (gy2 - ap.y > EPSF);
        }
        unsigned long long mb = __ballot(hit);
        if (hit) {
            int my = cnt + __popcll(mb & ((1ULL << lane) - 1ULL));
            if (my < WCAP) aidx[wave][my] = (unsigned short)a;
        }
        cnt += __popcll(mb);   // wave-uniform
    }
    if (cnt > WCAP) cnt = WCAP;

    // Phase B: dense metric pass, per-lane sorted top-13 in registers
    unsigned long long loc[TOPK];
    #pragma unroll
    for (int i = 0; i < TOPK; i++) loc[i] = 0ULL;
    const float4* pb4 = (const float4*)pred_bboxes;
    for (int p = lane; p < cnt; p += 64) {
        int a = aidx[wave][p];
        float4 pb = pb4[b * NA + a];
        float s = pred_scores[((size_t)b * NA + a) * NC + lab];
        float lx = fmaxf(gx1, pb.x), ly = fmaxf(gy1, pb.y);
        float rx = fminf(gx2, pb.z), ry = fminf(gy2, pb.w);
        float w = fmaxf(rx - lx, 0.f), h = fmaxf(ry - ly, 0.f);
        float inter = w * h;
        float aa = (gx2 - gx1) * (gy2 - gy1);
        float ab = (pb.z - pb.x) * (pb.w - pb.y);
        float iou = inter / (aa + ab - inter + EPSF);
        float i2 = iou * iou;
        float m = s * (i2 * i2 * i2);
        if (m > 0.f) {
            // (metric<<32)|(NA-a): u64 order == value desc, index asc (jax tie-break)
            unsigned long long key =
                ((unsigned long long)__float_as_uint(m) << 32) |
                (unsigned int)(NA - a);
            #pragma unroll
            for (int i = 0; i < TOPK; i++) {
                if (key > loc[i]) { unsigned long long tmp = loc[i]; loc[i] = key; key = tmp; }
            }
        }
    }

    // Phase C: 13 extract-max rounds; winner writes its OWN row's list slot
    int picks = TOPK;
    for (int r = 0; r < TOPK; r++) {
        unsigned long long h = loc[0];
        unsigned long long m = h;
        #pragma unroll
        for (int s = 32; s > 0; s >>= 1) {
            unsigned long long o = __shfl_xor(m, s, 64);
            m = o > m ? o : m;
        }
        if (m == 0ULL) { picks = r; break; }   // wave-uniform
        unsigned long long ball = __ballot(h == m);  // keys distinct -> one lane
        if (lane == (int)__builtin_ctzll(ball)) {
            #pragma unroll
            for (int i = 0; i < TOPK - 1; i++) loc[i] = loc[i + 1];
            loc[TOPK - 1] = 0ULL;
            int a = NA - (int)(unsigned int)(m & 0xFFFFFFFFULL);
            clist[row * TOPK + r] = (unsigned short)a;
        }
    }
    if (lane == 0) ccount[row] = (unsigned int)picks;
}

// K3 (33 x BS x 256): claim inversion + resolution. Round-6 change: the
// positives list is now PER-WAVE-OWNED — each wave writes its positives into
// its private 64-slot plist segment and its count via plain stores. The
// Round-4/5 single hot atomicAdd(pcount)-with-return (~4224 serialized
// same-L2-line round trips ~= the observed 56us wall, invariant to the
// Round-5 VALU cut) is GONE. Zero contended atomics remain.
__global__ __launch_bounds__(256) void resolve_kernel(
    const float* __restrict__ pred_scores,
    const float* __restrict__ pred_bboxes,
    const int*   __restrict__ gt_labels,
    const float* __restrict__ gt_bboxes,
    const unsigned int*   __restrict__ ccount,
    const unsigned short* __restrict__ clist,
    unsigned int* __restrict__ pa_bits, unsigned int* __restrict__ po_bits,
    unsigned int* __restrict__ wcount, uint4* __restrict__ plist,
    float* __restrict__ out)
{
    __shared__ float4 gtb[NMAX];
    __shared__ int    glab[NMAX];
    __shared__ int    ccnt[NMAX];
    __shared__ unsigned int pkl[256];
    int b = blockIdx.y;
    int t = threadIdx.x;
    int lane = t & 63;
    int lo = blockIdx.x * 256;
    int ai = lo + t;
    bool valid = ai < NA;
    int idx = b * NA + (valid ? ai : 0);

    // issue the coalesced per-anchor box load FIRST (covered by staging+sync)
    float4 pb = ((const float4*)pred_bboxes)[idx];

    if (t < NMAX) {
        gtb[t]  = ((const float4*)gt_bboxes)[b * NMAX + t];
        glab[t] = gt_labels[b * NMAX + t];
        ccnt[t] = (int)ccount[b * NMAX + t];
    }
    pkl[t] = 0u;
    __syncthreads();

    // invert claim lists into this block's anchor window (<=1300 entries)
    for (int e = t; e < NMAX * TOPK; e += 256) {
        int j = e / TOPK, k = e - j * TOPK;
        if (k < ccnt[j]) {
            int a = clist[(b * NMAX + j) * TOPK + k];
            unsigned int w = (unsigned int)(a - lo);
            if (w < 256u) atomicAdd(&pkl[w], (1u << 16) | (unsigned int)j);
        }
    }
    __syncthreads();

    unsigned int pk = valid ? pkl[t] : 0u;
    int js = -1; float iou = 0.f;

    if ((pk >> 16) == 1u) {          // single claim: direct reuse
        js = (int)(pk & 0xFFFFu);
        float4 g = gtb[js];
        float lx = fmaxf(g.x, pb.x), ly = fmaxf(g.y, pb.y);
        float rx = fminf(g.z, pb.z), ry = fminf(g.w, pb.w);
        float w = fmaxf(rx - lx, 0.f), h = fmaxf(ry - ly, 0.f);
        float inter = w * h;
        float aa = (g.z - g.x) * (g.w - g.y);
        float ab = (pb.z - pb.x) * (pb.w - pb.y);
        iou = inter / (aa + ab - inter + EPSF);
    }

    // cooperative multi-claim resolution (wave-uniform loop, ~1 hit/wave avg).
    // Tie-break: key=(iou_bits<<32)|(99-j) -> max picks smallest j on exact
    // ties == jax argmax first-max. IOUs >=0 so bit compare == float compare.
    unsigned long long mm = __ballot((pk >> 16) > 1u);
    while (mm) {
        int src = (int)__builtin_ctzll(mm);
        mm &= mm - 1ULL;
        float qx1 = __shfl(pb.x, src, 64), qy1 = __shfl(pb.y, src, 64);
        float qx2 = __shfl(pb.z, src, 64), qy2 = __shfl(pb.w, src, 64);
        float qab = (qx2 - qx1) * (qy2 - qy1);
        unsigned long long bestkey = 0ULL;
        #pragma unroll
        for (int rep = 0; rep < 2; rep++) {       // j = lane, lane+64 (<100)
            int j = lane + rep * 64;
            if (j < NMAX) {
                float4 g = gtb[j];
                float lx = fmaxf(g.x, qx1), ly = fmaxf(g.y, qy1);
                float rx = fminf(g.z, qx2), ry = fminf(g.w, qy2);
                float w = fmaxf(rx - lx, 0.f), h = fmaxf(ry - ly, 0.f);
                float inter = w * h;
                float aa = (g.z - g.x) * (g.w - g.y);
                float v = inter / (aa + qab - inter + EPSF);
                unsigned long long key =
                    ((unsigned long long)__float_as_uint(v) << 32) |
                    (unsigned int)(NMAX - 1 - j);
                if (key > bestkey) bestkey = key;
            }
        }
        #pragma unroll
        for (int s = 32; s > 0; s >>= 1) {
            unsigned long long o = __shfl_xor(bestkey, s, 64);
            bestkey = o > bestkey ? o : bestkey;
        }
        if (lane == src) {
            js  = NMAX - 1 - (int)(unsigned int)(bestkey & 0xFFFFFFFFULL);
            iou = __uint_as_float((unsigned int)(bestkey >> 32));
        }
    }

    float align = 0.f; int lab = 0;
    if (js >= 0) {
        lab = glab[js];
        float s = pred_scores[(size_t)idx * NC + lab];
        float i2 = iou * iou;
        align = s * (i2 * i2 * i2);   // UNMASKED align metric (reference semantics)
        // non-negative floats: uint bit-pattern compare == float compare;
        // 3200 distinct addresses, ~10 ops each -> no contention wall
        atomicMax(&pa_bits[b * NMAX + js], __float_as_uint(align));
        atomicMax(&po_bits[b * NMAX + js], __float_as_uint(iou));
    }

    if (valid) {
        bool pos = js >= 0;
        int j0 = pos ? js : 0;   // argmax of all-zero mask_pos -> gt 0
        out[OFF_LBL + idx] = pos ? (float)glab[j0] : (float)NC;
        ((float4*)(out + OFF_BOX))[idx] = gtb[j0];
        out[OFF_POS + idx] = pos ? 1.f : 0.f;
    }

    // per-wave-owned positives segment: plain stores, no atomics, no shuffles.
    // Every wave (incl. all-negative / partially-invalid ones) writes wcount.
    bool pos = valid && js >= 0;
    unsigned long long mb = __ballot(pos);
    int wid = (b * NCHUNK + blockIdx.x) * 4 + (t >> 6);
    if (lane == 0) wcount[wid] = (unsigned int)__popcll(mb);
    if (pos) {
        int myoff = __popcll(mb & ((1ULL << lane) - 1ULL));
        plist[wid * 64 + myoff] = make_uint4((unsigned int)idx,
                                             (unsigned int)(b * NMAX + js),
                                             __float_as_uint(align),
                                             (unsigned int)lab);
    }
}

// K4 (1056 x 256): one wave per plist segment, lane i handles slot i.
// wcount load is wave-uniform; ~30K scattered 4B stores into the pre-zeroed
// score region. pa/po complete after K3's dispatch boundary.
__global__ __launch_bounds__(256) void scatter_kernel(
    const unsigned int* __restrict__ wcount, const uint4* __restrict__ plist,
    const unsigned int* __restrict__ pa_bits, const unsigned int* __restrict__ po_bits,
    float* __restrict__ out)
{
    int wid = blockIdx.x * 4 + (threadIdx.x >> 6);
    int lane = threadIdx.x & 63;
    unsigned int n = wcount[wid];
    if ((unsigned int)lane < n) {
        uint4 e = plist[wid * 64 + lane];
        float pa = __uint_as_float(pa_bits[e.y]);
        float po = __uint_as_float(po_bits[e.y]);
        out[OFF_SCR + (size_t)e.x * NC + e.w] = __uint_as_float(e.z) * po / (pa + EPSF);
    }
}

extern "C" void kernel_launch(void* const* d_in, const int* in_sizes, int n_in,
                              void* d_out, int out_size, void* d_ws, size_t ws_size,
                              hipStream_t stream) {
    const float* pred_scores   = (const float*)d_in[0];
    const float* pred_bboxes   = (const float*)d_in[1];
    const float* anchor_points = (const float*)d_in[2];
    const int*   gt_labels     = (const int*)d_in[3];
    const float* gt_bboxes     = (const float*)d_in[4];
    const float* mask_gt       = (const float*)d_in[5];

    char* ws = (char*)d_ws;
    // ws layout (no host-side init; ws may be poisoned 0xAA each launch):
    //   [pa 3200 u32][po 3200 u32]        <- zeroed by K1 block 1
    //   [ccount 3200 u32]                 <- fully written by K2
    //   [clist 3200*13 u16]               <- slots < ccount written by K2
    //   [strip_off 65 int (512B pad)][sAPI 8400 float4]  <- written by K1 blk 0
    //   [wcount 4224 u32]                 <- fully written by K3 (plain stores)
    //   [plist 4224*64 uint4]             <- slots < wcount written by K3
    unsigned int*   pa_bits = (unsigned int*)(ws);
    unsigned int*   po_bits = (unsigned int*)(ws + 12800);
    unsigned int*   ccount  = (unsigned int*)(ws + 25600);
    unsigned short* clist   = (unsigned short*)(ws + 38400);
    int*    strip_off = (int*)(ws + 121600);             // 38400+83200
    float4* sAPI      = (float4*)(ws + 122112);          // +512 pad
    unsigned int* wcount = (unsigned int*)(ws + 256512); // +8400*16
    uint4*  plist     = (uint4*)(ws + 273408);           // +4224*4 (16B-aligned)

    float* out = (float*)d_out;

    // 4 dispatches, 0 memsets, 0 contended atomics:
    bin_zero_kernel<<<1 + ZBLK, 1024, 0, stream>>>(
        anchor_points, strip_off, sAPI, pa_bits, out);

    topk_kernel<<<NROWS / 4, 256, 0, stream>>>(
        pred_scores, pred_bboxes, gt_labels, gt_bboxes, mask_gt,
        strip_off, sAPI, ccount, clist);

    dim3 rgrid(NCHUNK, BS);
    resolve_kernel<<<rgrid, 256, 0, stream>>>(
        pred_scores, pred_bboxes, gt_labels, gt_bboxes, ccount, clist,
        pa_bits, po_bits, wcount, plist, out);

    scatter_kernel<<<NWID / 4, 256, 0, stream>>>(
        wcount, plist, pa_bits, po_bits, out);
}